// Round 17
// baseline (2169.291 us; speedup 1.0000x reference)
//
#include <hip/hip_runtime.h>
#include <hip/hip_bf16.h>
#include <math.h>

#define VOCAB 1500
#define NE    208
#define TT    256
#define NHD   4
#define HD    52
#define NL    8
#define BBATCH 256
#define NTOK  (BBATCH * TT)   // 65536
#define KP    224             // NE padded to multiple of 32

typedef __attribute__((ext_vector_type(8))) short bf16x8;
typedef __attribute__((ext_vector_type(4))) short s16x4;
typedef __attribute__((ext_vector_type(4))) float f32x4;
typedef __attribute__((ext_vector_type(4))) int i32x4;
typedef __attribute__((ext_vector_type(4))) _Float16 f16x4;

__device__ __forceinline__ void gload16(const void* g, void* l) {
  __builtin_amdgcn_global_load_lds(
      (const __attribute__((address_space(1))) unsigned int*)g,
      (__attribute__((address_space(3))) unsigned int*)l, 16, 0, 0);
}
__device__ __forceinline__ float bf2f(short u) {
  union { unsigned int i; float f; } cv;
  cv.i = ((unsigned int)(unsigned short)u) << 16;
  return cv.f;
}
__device__ __forceinline__ short f2bf(float f) {
  return (short)__bfloat16_as_ushort(__float2bfloat16(f));
}

// ---------- merged weight prep: all transposed/padded bf16 copies ----------
// QKV packed per-head: [NL][NHD][256][KP], rows: q 0-51 | k 52-103 | v 104-155 | 0
#define P_QKVH 1835008           // NL*NHD*256*KP
#define P_O    458752            // NL*256*KP
#define P_1    1605632           // NL*896*KP
#define P_2    1703936           // NL*256*832
#define P_LM   344064            // 1536*KP
__global__ __launch_bounds__(256) void k_prep_all(const float* __restrict__ Wq,
                                                  const float* __restrict__ Wk,
                                                  const float* __restrict__ Wv,
                                                  const float* __restrict__ Wo,
                                                  const float* __restrict__ W1,
                                                  const float* __restrict__ W2,
                                                  const float* __restrict__ Wlm,
                                                  __hip_bfloat16* __restrict__ qkvH,
                                                  __hip_bfloat16* __restrict__ oT,
                                                  __hip_bfloat16* __restrict__ t1,
                                                  __hip_bfloat16* __restrict__ t2,
                                                  __hip_bfloat16* __restrict__ lmT) {
  int gi = blockIdx.x * 256 + threadIdx.x;
  if (gi < P_QKVH) {
    int i = gi;
    int c = i % KP;
    int rhl = i / KP;
    int r = rhl % 256, hl = rhl / 256;
    int h = hl % NHD, l = hl / NHD;
    float v = 0.f;
    if (c < NE && r < 156) {
      const float* W = (r < 52) ? Wq : (r < 104) ? Wk : Wv;
      int d = (r < 52) ? r : (r < 104) ? r - 52 : r - 104;
      v = W[(((size_t)l * NHD + h) * NE + c) * HD + d];
    }
    qkvH[i] = __float2bfloat16(v);
  } else if (gi < P_QKVH + P_O) {
    int i = gi - P_QKVH;
    int c = i % KP;
    int jl = i / KP;
    int j = jl % 256, l = jl / 256;
    float v = (j < NE && c < NE) ? Wo[((size_t)l * NE + c) * NE + j] : 0.f;
    oT[i] = __float2bfloat16(v);
  } else if (gi < P_QKVH + P_O + P_1) {
    int i = gi - (P_QKVH + P_O);
    int c = i % KP;
    int jl = i / KP;
    int j = jl % 896, l = jl / 896;
    float v = (j < 832 && c < NE) ? W1[((size_t)l * NE + c) * 832 + j] : 0.f;
    t1[i] = __float2bfloat16(v);
  } else if (gi < P_QKVH + P_O + P_1 + P_2) {
    int i = gi - (P_QKVH + P_O + P_1);
    int c = i % 832;
    int jl = i / 832;
    int j = jl % 256, l = jl / 256;
    float v = (j < NE) ? W2[((size_t)l * 832 + c) * NE + j] : 0.f;
    t2[i] = __float2bfloat16(v);
  } else {
    int i = gi - (P_QKVH + P_O + P_1 + P_2);
    int c = i % KP;
    int j = i / KP;
    float v = (j < VOCAB && c < NE) ? Wlm[(size_t)c * VOCAB + j] : 0.f;
    lmT[i] = __float2bfloat16(v);
  }
}

// --- fused embedding + LayerNorm1; also zero hattn pad cols (once) ---------
__global__ __launch_bounds__(256) void k_embed_ln(const int* __restrict__ idx,
                                                  const float* __restrict__ tok,
                                                  const float* __restrict__ pos,
                                                  const float* __restrict__ g,
                                                  const float* __restrict__ b,
                                                  __hip_bfloat16* __restrict__ x,
                                                  __hip_bfloat16* __restrict__ h,
                                                  __hip_bfloat16* __restrict__ hattn) {
  int r = blockIdx.x * 4 + (threadIdx.x >> 6);
  int lane = threadIdx.x & 63;
  const int c0 = lane * 4;
  const int t = r & (TT - 1);
  float v[4] = {0.f, 0.f, 0.f, 0.f};
  float s = 0.f;
  if (lane < 52) {
    float4 tv = *(const float4*)(tok + (size_t)idx[r] * NE + c0);
    float4 pv = *(const float4*)(pos + (size_t)t * NE + c0);
    v[0] = tv.x + pv.x; v[1] = tv.y + pv.y;
    v[2] = tv.z + pv.z; v[3] = tv.w + pv.w;
    s = v[0] + v[1] + v[2] + v[3];
  }
  #pragma unroll
  for (int o = 32; o; o >>= 1) s += __shfl_xor(s, o);
  float mu = s * (1.f / NE);
  float q = 0.f;
  if (lane < 52) {
    #pragma unroll
    for (int i = 0; i < 4; i++) { float d = v[i] - mu; q += d * d; }
  }
  #pragma unroll
  for (int o = 32; o; o >>= 1) q += __shfl_xor(q, o);
  float inv = rsqrtf(q * (1.f / NE) + 1e-5f);
  if (lane < 52) {
    s16x4 xv;
    #pragma unroll
    for (int i = 0; i < 4; i++) xv[i] = f2bf(v[i]);
    *(s16x4*)(x + (size_t)r * NE + c0) = xv;
  }
  if (lane < 56) {
    s16x4 outv = {};
    if (lane < 52) {
      #pragma unroll
      for (int i = 0; i < 4; i++)
        outv[i] = f2bf((v[i] - mu) * inv * g[c0 + i] + b[c0 + i]);
    }
    *(s16x4*)(h + (size_t)r * KP + c0) = outv;
    if (lane >= 52)   // zero hattn pad cols 208..223 (never written by attn)
      *(s16x4*)(hattn + (size_t)r * KP + c0) = (s16x4){};
  }
}

// ------- bf16 MFMA GEMM (LM head) + XCD swizzle + fused exp-sum ------------
template <bool RELU, bool BIAS, bool OUTBF, bool EXPSUM>
__global__ __launch_bounds__(256) void k_mgemm(const __hip_bfloat16* __restrict__ A, int lda,
                                               const __hip_bfloat16* __restrict__ BT, int ldb,
                                               const float* __restrict__ bias,
                                               void* __restrict__ Cout, int ldc,
                                               int N, int K,
                                               float* __restrict__ esum) {
  __shared__ __hip_bfloat16 As[2][128 * 32];
  __shared__ __hip_bfloat16 Bs[2][128 * 32];
  const int gx = gridDim.x;
  const int id = blockIdx.x + gx * blockIdx.y;
  const int qq = (gx * gridDim.y) >> 3;          // nwg % 8 == 0 (gridDim.y=512)
  const int wid2 = (id & 7) * qq + (id >> 3);
  const int by = wid2 / gx, bx = wid2 - by * gx;
  const int bm = by * 128, bn = bx * 128;
  const int tid = threadIdx.x;
  const int wave = tid >> 6, lane = tid & 63;
  const int wr = (wave >> 1) * 64, wc = (wave & 1) * 64;
  const int l15 = lane & 15, l4 = lane >> 4;
  const int srow = tid >> 2, sgrp = (tid & 3) * 8;
  const int srow2 = srow + 64;
  f32x4 acc[4][4] = {};
  const int nt = K / 32;
  gload16(A + (size_t)(bm + srow) * lda + sgrp, &As[0][tid * 8]);
  gload16(BT + (size_t)(bn + srow) * ldb + sgrp, &Bs[0][tid * 8]);
  gload16(A + (size_t)(bm + srow2) * lda + sgrp, &As[0][(256 + tid) * 8]);
  gload16(BT + (size_t)(bn + srow2) * ldb + sgrp, &Bs[0][(256 + tid) * 8]);
  int cur = 0;
  for (int t = 0; t < nt; t++) {
    if (t + 1 < nt) {
      int k1 = (t + 1) * 32;
      gload16(A + (size_t)(bm + srow) * lda + k1 + sgrp, &As[cur ^ 1][tid * 8]);
      gload16(BT + (size_t)(bn + srow) * ldb + k1 + sgrp, &Bs[cur ^ 1][tid * 8]);
      gload16(A + (size_t)(bm + srow2) * lda + k1 + sgrp, &As[cur ^ 1][(256 + tid) * 8]);
      gload16(BT + (size_t)(bn + srow2) * ldb + k1 + sgrp, &Bs[cur ^ 1][(256 + tid) * 8]);
      asm volatile("s_waitcnt vmcnt(4)" ::: "memory");
    } else {
      asm volatile("s_waitcnt vmcnt(0)" ::: "memory");
    }
    __builtin_amdgcn_s_barrier();
    bf16x8 af[4], bfr[4];
    #pragma unroll
    for (int m = 0; m < 4; m++)
      af[m] = *(const bf16x8*)&As[cur][(wr + m * 16 + l15) * 32 + l4 * 8];
    #pragma unroll
    for (int n = 0; n < 4; n++)
      bfr[n] = *(const bf16x8*)&Bs[cur][(wc + n * 16 + l15) * 32 + l4 * 8];
    #pragma unroll
    for (int m = 0; m < 4; m++)
      #pragma unroll
      for (int n = 0; n < 4; n++)
        acc[m][n] = __builtin_amdgcn_mfma_f32_16x16x32_bf16(af[m], bfr[n], acc[m][n], 0, 0, 0);
    if (t + 1 < nt) __builtin_amdgcn_s_barrier();
    cur ^= 1;
  }
  float es[4][4];
  if (EXPSUM) {
    #pragma unroll
    for (int m = 0; m < 4; m++)
      #pragma unroll
      for (int j = 0; j < 4; j++) es[m][j] = 0.f;
  }
  #pragma unroll
  for (int m = 0; m < 4; m++) {
    #pragma unroll
    for (int n = 0; n < 4; n++) {
      int col = bn + wc + n * 16 + l15;
      if (col < N) {
        float bv = BIAS ? bias[col] : 0.f;
        #pragma unroll
        for (int j = 0; j < 4; j++) {
          int row = bm + wr + m * 16 + l4 * 4 + j;
          float v = acc[m][n][j] + bv;
          if (RELU) v = fmaxf(v, 0.f);
          size_t off = (size_t)row * ldc + col;
          if (OUTBF) ((__hip_bfloat16*)Cout)[off] = __float2bfloat16(v);
          else       ((float*)Cout)[off] = v;
          if (EXPSUM) es[m][j] += __expf(v);   // |v| small: no-max exp safe
        }
      }
    }
  }
  if (EXPSUM) {
    #pragma unroll
    for (int m = 0; m < 4; m++)
      #pragma unroll
      for (int j = 0; j < 4; j++) {
        float e = es[m][j];
        #pragma unroll
        for (int off = 1; off < 16; off <<= 1) e += __shfl_xor(e, off);
        if (l15 == 0) {
          int row = bm + wr + m * 16 + l4 * 4 + j;
          esum[(size_t)row * 24 + bx * 2 + (wave & 1)] = e;
        }
      }
  }
}

// ---- fused per-head QKV GEMM + flash attention: one block per (b,h) -------
__global__ __launch_bounds__(512) void k_qkv_attn(const __hip_bfloat16* __restrict__ hbf,
                                                  const __hip_bfloat16* __restrict__ WqkvH,
                                                  __hip_bfloat16* __restrict__ o) {
  __shared__ __hip_bfloat16 As2[2][256 * 32];   // 32 KB
  __shared__ __hip_bfloat16 Bs2[2][256 * 32];   // 32 KB
  __shared__ __hip_bfloat16 Ks[256 * 64];       // 32 KB
  __shared__ _Float16      Vt[64 * 260];        // 32.5 KB
  __shared__ __hip_bfloat16 Qs[256 * 56];       // 28 KB   (total 156.5 KB)
  const int bh0 = blockIdx.x;
  const int bh = (bh0 & 7) * 128 + (bh0 >> 3);  // 4 heads of b on one XCD
  const int b = bh >> 2, h = bh & 3;
  const __hip_bfloat16* A = hbf + (size_t)b * TT * KP;
  const __hip_bfloat16* B = WqkvH + (size_t)h * 256 * KP;
  const int tid = threadIdx.x;
  const int w = tid >> 6, lane = tid & 63, l15 = lane & 15, l4 = lane >> 4;
  // ---------------- phase 1: QKV GEMM ----------------
  {
    const int s0 = tid, s1 = tid + 512;
    const int r0 = s0 >> 2, g0 = (s0 & 3) * 8;
    const int r1 = s1 >> 2, g1 = (s1 & 3) * 8;
    f32x4 acc[2][10] = {};
    gload16(A + (size_t)r0 * KP + g0, &As2[0][s0 * 8]);
    gload16(A + (size_t)r1 * KP + g1, &As2[0][s1 * 8]);
    gload16(B + (size_t)r0 * KP + g0, &Bs2[0][s0 * 8]);
    gload16(B + (size_t)r1 * KP + g1, &Bs2[0][s1 * 8]);
    int cur = 0;
    for (int t = 0; t < 7; t++) {
      if (t < 6) {
        int k1 = (t + 1) * 32;
        gload16(A + (size_t)r0 * KP + k1 + g0, &As2[cur ^ 1][s0 * 8]);
        gload16(A + (size_t)r1 * KP + k1 + g1, &As2[cur ^ 1][s1 * 8]);
        gload16(B + (size_t)r0 * KP + k1 + g0, &Bs2[cur ^ 1][s0 * 8]);
        gload16(B + (size_t)r1 * KP + k1 + g1, &Bs2[cur ^ 1][s1 * 8]);
        asm volatile("s_waitcnt vmcnt(4)" ::: "memory");
      } else {
        asm volatile("s_waitcnt vmcnt(0)" ::: "memory");
      }
      __builtin_amdgcn_s_barrier();
      bf16x8 af[2], bfr[10];
      #pragma unroll
      for (int m = 0; m < 2; m++)
        af[m] = *(const bf16x8*)&As2[cur][(w * 32 + m * 16 + l15) * 32 + l4 * 8];
      #pragma unroll
      for (int n = 0; n < 10; n++)
        bfr[n] = *(const bf16x8*)&Bs2[cur][(n * 16 + l15) * 32 + l4 * 8];
      #pragma unroll
      for (int m = 0; m < 2; m++)
        #pragma unroll
        for (int n = 0; n < 10; n++)
          acc[m][n] = __builtin_amdgcn_mfma_f32_16x16x32_bf16(af[m], bfr[n], acc[m][n], 0, 0, 0);
      if (t < 6) __builtin_amdgcn_s_barrier();
      cur ^= 1;
    }
    // scatter: Q -> Qs[t][d], K -> Ks[t][d], V -> Vt[d][t] (f32->f16 direct)
    #pragma unroll
    for (int m = 0; m < 2; m++)
      #pragma unroll
      for (int n = 0; n < 10; n++) {
        int col = n * 16 + l15;
        #pragma unroll
        for (int j = 0; j < 4; j++) {
          int trow = w * 32 + m * 16 + l4 * 4 + j;
          float v = acc[m][n][j];
          if (col < 52)        Qs[trow * 56 + col] = __float2bfloat16(v);
          else if (col < 104)  Ks[trow * 64 + (col - 52)] = __float2bfloat16(v);
          else if (col < 156)  Vt[(col - 104) * 260 + trow] = (_Float16)v;
        }
      }
  }
  // zero pads (R9 lesson: uninit LDS can be NaN bits; every read slot written)
  for (int i = tid; i < 768; i += 512) {        // Ks cols 52..63
    int row = i / 3, cc = 52 + (i % 3) * 4;
    *(s16x4*)&Ks[row * 64 + cc] = (s16x4){};
  }
  for (int i = tid; i < 3072; i += 512)         // Vt rows 52..63
    Vt[(52 + i / 256) * 260 + (i & 255)] = (_Float16)0.f;
  if (tid < 256)                                // Qs cols 52..55
    *(s16x4*)&Qs[tid * 56 + 52] = (s16x4){};
  __syncthreads();
  // ---------------- phase 2: attention ----------------
  const float scale = 0.06933752453f;  // NE**-0.5 (reference scales by n_embed)
  const int qts[2] = {w, 15 - w};
  bf16x8 qf[2][2];
  #pragma unroll
  for (int i = 0; i < 2; i++)
    #pragma unroll
    for (int ks = 0; ks < 2; ks++) {
      int s = ks * 32 + l4 * 8;
      qf[i][ks] = (s <= 48) ? *(const bf16x8*)&Qs[(qts[i] * 16 + l15) * 56 + s]
                            : (bf16x8){};
    }
  f32x4 oacc[4][2] = {};
  float mrun[2] = {-1e30f, -1e30f};
  float lrun[2] = {0.f, 0.f};
  const int cmax = 15 - w;
  for (int c = 0; c <= cmax; c++) {
    const int kb = c * 16;
    const bf16x8 kf0 = *(const bf16x8*)&Ks[(kb + l15) * 64 + l4 * 8];
    const bf16x8 kf1 = *(const bf16x8*)&Ks[(kb + l15) * 64 + 32 + l4 * 8];
    #pragma unroll
    for (int i = 0; i < 2; i++) {
      if (qts[i] < c) continue;
      __builtin_amdgcn_s_setprio(1);
      f32x4 s4 = __builtin_amdgcn_mfma_f32_16x16x32_bf16(kf0, qf[i][0],
                                                         (f32x4){0.f, 0.f, 0.f, 0.f}, 0, 0, 0);
      s4 = __builtin_amdgcn_mfma_f32_16x16x32_bf16(kf1, qf[i][1], s4, 0, 0, 0);
      __builtin_amdgcn_s_setprio(0);
      const int q = qts[i] * 16 + l15;
      float pv[4];
      float pmax = -1e30f;
      #pragma unroll
      for (int j = 0; j < 4; j++) {
        int key = kb + l4 * 4 + j;
        float s = s4[j] * scale;
        pv[j] = (key <= q) ? s : -1e30f;
        pmax = fmaxf(pmax, pv[j]);
      }
      pmax = fmaxf(pmax, __shfl_xor(pmax, 16));
      pmax = fmaxf(pmax, __shfl_xor(pmax, 32));
      if (!__all(pmax - mrun[i] <= 8.f)) {     // T13 defer-rescale
        const float newm = fmaxf(mrun[i], pmax);
        const float r = __expf(mrun[i] - newm);
        lrun[i] *= r;
        mrun[i] = newm;
        #pragma unroll
        for (int m = 0; m < 4; m++) {
          oacc[m][i][0] *= r; oacc[m][i][1] *= r;
          oacc[m][i][2] *= r; oacc[m][i][3] *= r;
        }
      }
      float psum = 0.f;
      f16x4 pb;
      #pragma unroll
      for (int j = 0; j < 4; j++) {
        float e = __expf(pv[j] - mrun[i]);   // bounded by e^8
        psum += e;
        pb[j] = (_Float16)e;
      }
      psum += __shfl_xor(psum, 16);
      psum += __shfl_xor(psum, 32);
      lrun[i] += psum;
      __builtin_amdgcn_s_setprio(1);
      #pragma unroll
      for (int m = 0; m < 4; m++) {
        f16x4 vf = *(const f16x4*)&Vt[(m * 16 + l15) * 260 + kb + l4 * 4];
        oacc[m][i] = __builtin_amdgcn_mfma_f32_16x16x16f16(vf, pb, oacc[m][i], 0, 0, 0);
      }
      __builtin_amdgcn_s_setprio(0);
    }
  }
  #pragma unroll
  for (int i = 0; i < 2; i++) {
    const float inv = 1.f / lrun[i];
    __hip_bfloat16* orow = o + (size_t)(b * TT + qts[i] * 16 + l15) * KP + h * HD;
    #pragma unroll
    for (int m = 0; m < 4; m++) {
      int d0 = m * 16 + l4 * 4;
      if (d0 + 3 < HD) {               // 13 packed 8B stores
        s16x4 pk;
        #pragma unroll
        for (int j = 0; j < 4; j++) pk[j] = f2bf(oacc[m][i][j] * inv);
        *(s16x4*)(orow + d0) = pk;
      }
    }
  }
}

// ---- fused layer-2nd-half: x''=x+attn@Wo+bo thru MLP, dual LN, 1 kernel ---
// Phase C now software-pipelines the weight fetches: W1(jc+1) issued during
// GEMM2(jc); W2(jc) drained only at the post-GEMM1 __syncthreads (hidden).
__global__ __launch_bounds__(512) void k_wo_mlp_ln(const __hip_bfloat16* __restrict__ hattn,
                                                   const __hip_bfloat16* __restrict__ WoT,
                                                   const float* __restrict__ bo,
                                                   const __hip_bfloat16* __restrict__ W1T,
                                                   const float* __restrict__ b1,
                                                   const __hip_bfloat16* __restrict__ W2T,
                                                   const float* __restrict__ b2,
                                                   const float* __restrict__ g2,
                                                   const float* __restrict__ bb2,
                                                   const float* __restrict__ gn,
                                                   const float* __restrict__ bn,
                                                   __hip_bfloat16* __restrict__ xio,
                                                   __hip_bfloat16* __restrict__ hout) {
  __shared__ __hip_bfloat16 Hs[128 * 232];       // 59.4 KB (LN(x'), MLP A-tile)
  __shared__ __hip_bfloat16 pool[39936];         // 78 KB union
  __hip_bfloat16 (*As)[128 * 32] = (__hip_bfloat16 (*)[128 * 32])pool;
  __hip_bfloat16 (*Bs)[256 * 32] = (__hip_bfloat16 (*)[256 * 32])(pool + 8192);
  __hip_bfloat16* W1s = pool;
  __hip_bfloat16* Ac  = pool + 14336;
  __hip_bfloat16 (*W2s)[256 * 32] = (__hip_bfloat16 (*)[256 * 32])(pool + 23552);
  __shared__ float sred[128][4], qred[128][4];
  const int bm = blockIdx.x * 128;
  const int tid = threadIdx.x;
  const int wid = tid >> 6, lane = tid & 63;
  const int l15 = lane & 15, l4 = lane >> 4;
  const int w2r = (wid >> 2) * 64, w2c = (wid & 3) * 64;
  const int w1r = (wid >> 1) * 32, w1c = (wid & 1) * 32;
  const int srow = tid >> 2, sgrp = (tid & 3) * 8;
  // ---------------- Phase A: Wo GEMM (K=224), acc = xp ----------------
  f32x4 xp[4][4] = {};
  {
    gload16(hattn + (size_t)(bm + srow) * KP + sgrp, &As[0][tid * 8]);
    gload16(WoT + (size_t)srow * KP + sgrp, &Bs[0][tid * 8]);
    gload16(WoT + (size_t)(128 + srow) * KP + sgrp, &Bs[0][(512 + tid) * 8]);
    int cur = 0;
    for (int t = 0; t < 7; t++) {
      if (t + 1 < 7) {
        int k1 = (t + 1) * 32;
        gload16(hattn + (size_t)(bm + srow) * KP + k1 + sgrp, &As[cur ^ 1][tid * 8]);
        gload16(WoT + (size_t)srow * KP + k1 + sgrp, &Bs[cur ^ 1][tid * 8]);
        gload16(WoT + (size_t)(128 + srow) * KP + k1 + sgrp, &Bs[cur ^ 1][(512 + tid) * 8]);
        asm volatile("s_waitcnt vmcnt(3)" ::: "memory");
      } else {
        asm volatile("s_waitcnt vmcnt(0)" ::: "memory");
      }
      __builtin_amdgcn_s_barrier();
      bf16x8 af[4], bfr[4];
      #pragma unroll
      for (int m = 0; m < 4; m++)
        af[m] = *(const bf16x8*)&As[cur][(w2r + m * 16 + l15) * 32 + l4 * 8];
      #pragma unroll
      for (int n = 0; n < 4; n++)
        bfr[n] = *(const bf16x8*)&Bs[cur][(w2c + n * 16 + l15) * 32 + l4 * 8];
      #pragma unroll
      for (int m = 0; m < 4; m++)
        #pragma unroll
        for (int n = 0; n < 4; n++)
          xp[m][n] = __builtin_amdgcn_mfma_f32_16x16x32_bf16(af[m], bfr[n], xp[m][n], 0, 0, 0);
      if (t + 1 < 7) __builtin_amdgcn_s_barrier();
      cur ^= 1;
    }
  }
  // ---- Epi A: x' = acc + bo + x (regs); LN2 stats; LN(x') -> Hs ----
  #pragma unroll
  for (int m = 0; m < 4; m++)
    #pragma unroll
    for (int j = 0; j < 4; j++) {
      int rowL = w2r + m * 16 + l4 * 4 + j;
      float s = 0.f, q = 0.f;
      #pragma unroll
      for (int n = 0; n < 4; n++) {
        int col = w2c + n * 16 + l15;
        float v = 0.f;
        if (col < NE)
          v = xp[m][n][j] + bo[col] +
              bf2f(((const short*)xio)[(size_t)(bm + rowL) * NE + col]);
        xp[m][n][j] = v;
        s += v; q += v * v;
      }
      #pragma unroll
      for (int off = 1; off < 16; off <<= 1) {
        s += __shfl_xor(s, off);
        q += __shfl_xor(q, off);
      }
      if (l15 == 0) { sred[rowL][wid & 3] = s; qred[rowL][wid & 3] = q; }
    }
  __syncthreads();   // sred/qred ready; all As/Bs ds_reads done -> pool free
  // issue W1(0) now: its fetch hides under the LN-write + zero-pad + barrier
  for (int s = tid; s < 1792; s += 512)
    gload16(W1T + (size_t)(s / 28) * KP + (s % 28) * 8, &W1s[s * 8]);
  #pragma unroll
  for (int m = 0; m < 4; m++)
    #pragma unroll
    for (int j = 0; j < 4; j++) {
      int rowL = w2r + m * 16 + l4 * 4 + j;
      float s = sred[rowL][0] + sred[rowL][1] + sred[rowL][2] + sred[rowL][3];
      float q = qred[rowL][0] + qred[rowL][1] + qred[rowL][2] + qred[rowL][3];
      float mu = s * (1.f / NE);
      float var = q * (1.f / NE) - mu * mu;
      float inv = rsqrtf(var + 1e-5f);
      #pragma unroll
      for (int n = 0; n < 4; n++) {
        int col = w2c + n * 16 + l15;
        if (col < NE)
          Hs[rowL * 232 + col] =
              __float2bfloat16((xp[m][n][j] - mu) * inv * g2[col] + bb2[col]);
      }
    }
  {
    int row = tid >> 2, c0 = 208 + (tid & 3) * 4;
    *(s16x4*)&Hs[row * 232 + c0] = (s16x4){};
  }
  __syncthreads();   // Hs complete (note: does NOT drain W1(0) vmcnt... it
                     // does (__syncthreads drains vmcnt(0)) -- acceptable:
                     // W1(0) had the whole epilogue to arrive.
  // ------- Phase C: MLP 13 chunks, pipelined weight fetches -------
  f32x4 acc2[4][4] = {};
  for (int jc = 0; jc < 13; jc++) {
    if (jc) __syncthreads();                   // B0: GEMM2(jc-1) W2s reads done
    for (int s = tid; s < 2048; s += 512) {    // issue W2(jc)
      int kt2 = s >> 10, ss = s & 1023;
      gload16(W2T + (size_t)(ss >> 2) * 832 + jc * 64 + kt2 * 32 + (ss & 3) * 8,
              &W2s[kt2][ss * 8]);
    }
    // wait only W1(jc) (oldest; W2 stays in flight across the barrier)
    asm volatile("s_waitcnt vmcnt(4)" ::: "memory");
    __builtin_amdgcn_s_barrier();              // B1: W1s visible to all waves
    f32x4 acc1[2][2] = {};
    #pragma unroll
    for (int kt = 0; kt < 7; kt++) {
      bf16x8 a0 = *(const bf16x8*)&Hs[(w1r + l15) * 232 + kt * 32 + l4 * 8];
      bf16x8 a1 = *(const bf16x8*)&Hs[(w1r + 16 + l15) * 232 + kt * 32 + l4 * 8];
      bf16x8 c0 = *(const bf16x8*)&W1s[(w1c + l15) * 224 + kt * 32 + l4 * 8];
      bf16x8 c1 = *(const bf16x8*)&W1s[(w1c + 16 + l15) * 224 + kt * 32 + l4 * 8];
      acc1[0][0] = __builtin_amdgcn_mfma_f32_16x16x32_bf16(a0, c0, acc1[0][0], 0, 0, 0);
      acc1[0][1] = __builtin_amdgcn_mfma_f32_16x16x32_bf16(a0, c1, acc1[0][1], 0, 0, 0);
      acc1[1][0] = __builtin_amdgcn_mfma_f32_16x16x32_bf16(a1, c0, acc1[1][0], 0, 0, 0);
      acc1[1][1] = __builtin_amdgcn_mfma_f32_16x16x32_bf16(a1, c1, acc1[1][1], 0, 0, 0);
    }
    #pragma unroll
    for (int m = 0; m < 2; m++)
      #pragma unroll
      for (int n = 0; n < 2; n++) {
        int colL = w1c + n * 16 + l15;
        float bv = b1[jc * 64 + colL];
        #pragma unroll
        for (int j = 0; j < 4; j++) {
          int rowL = w1r + m * 16 + l4 * 4 + j;
          Ac[rowL * 72 + colL] = __float2bfloat16(fmaxf(acc1[m][n][j] + bv, 0.f));
        }
      }
    __syncthreads();  // B2: Ac visible; drains W2(jc) too (hidden under GEMM1)
    if (jc < 12)      // issue W1(jc+1): W1s safe (all GEMM1 reads done at B2);
      for (int s = tid; s < 1792; s += 512)    // hides under GEMM2 + B0 + W2-issue
        gload16(W1T + (size_t)((jc + 1) * 64 + s / 28) * KP + (s % 28) * 8, &W1s[s * 8]);
    #pragma unroll
    for (int kt2 = 0; kt2 < 2; kt2++) {
      bf16x8 af[4], bfr[4];
      #pragma unroll
      for (int m = 0; m < 4; m++)
        af[m] = *(const bf16x8*)&Ac[(w2r + m * 16 + l15) * 72 + kt2 * 32 + l4 * 8];
      #pragma unroll
      for (int n = 0; n < 4; n++)
        bfr[n] = *(const bf16x8*)&W2s[kt2][(w2c + n * 16 + l15) * 32 + l4 * 8];
      #pragma unroll
      for (int m = 0; m < 4; m++)
        #pragma unroll
        for (int n = 0; n < 4; n++)
          acc2[m][n] = __builtin_amdgcn_mfma_f32_16x16x32_bf16(af[m], bfr[n], acc2[m][n], 0, 0, 0);
    }
  }
  // ---- Epi C: x'' = xp + mlp + b2; LN-next; stores ----
  #pragma unroll
  for (int m2 = 0; m2 < 4; m2++)
    #pragma unroll
    for (int j = 0; j < 4; j++) {
      int rowL = w2r + m2 * 16 + l4 * 4 + j;
      float s = 0.f, q = 0.f;
      #pragma unroll
      for (int n2 = 0; n2 < 4; n2++) {
        int col = w2c + n2 * 16 + l15;
        float v = 0.f;
        if (col < NE) v = acc2[m2][n2][j] + b2[col] + xp[m2][n2][j];
        acc2[m2][n2][j] = v;
        s += v; q += v * v;
      }
      #pragma unroll
      for (int off = 1; off < 16; off <<= 1) {
        s += __shfl_xor(s, off);
        q += __shfl_xor(q, off);
      }
      if (l15 == 0) { sred[rowL][wid & 3] = s; qred[rowL][wid & 3] = q; }
    }
  __syncthreads();
  #pragma unroll
  for (int m2 = 0; m2 < 4; m2++)
    #pragma unroll
    for (int j = 0; j < 4; j++) {
      int rowL = w2r + m2 * 16 + l4 * 4 + j;
      float s = sred[rowL][0] + sred[rowL][1] + sred[rowL][2] + sred[rowL][3];
      float q = qred[rowL][0] + qred[rowL][1] + qred[rowL][2] + qred[rowL][3];
      float mu = s * (1.f / NE);
      float var = q * (1.f / NE) - mu * mu;
      float inv = rsqrtf(var + 1e-5f);
      size_t row = bm + rowL;
      #pragma unroll
      for (int n2 = 0; n2 < 4; n2++) {
        int col = w2c + n2 * 16 + l15;
        if (col < NE) {
          float v = acc2[m2][n2][j];
          xio[row * NE + col] = __float2bfloat16(v);
          hout[row * KP + col] = __float2bfloat16((v - mu) * inv * gn[col] + bn[col]);
        } else if (col < KP) {
          hout[row * KP + col] = __float2bfloat16(0.f);
        }
      }
    }
}

// ---------------- loss from fused exp-sums ----------------
__global__ __launch_bounds__(256) void k_loss_fin(const float* __restrict__ esum,
                                                  const float* __restrict__ logits,
                                                  const int* __restrict__ targets,
                                                  float* __restrict__ row_loss) {
  int r = blockIdx.x * 256 + threadIdx.x;
  const float* e = esum + (size_t)r * 24;
  float s = 0.f;
  #pragma unroll
  for (int i = 0; i < 24; i++) s += e[i];
  row_loss[r] = __logf(s) - logits[(size_t)r * VOCAB + targets[r]];
}

__global__ __launch_bounds__(256) void k_loss_reduce(const float* __restrict__ row_loss,
                                                     float* __restrict__ out_loss) {
  __shared__ float sh[256];
  float s = 0.f;
  for (int i = threadIdx.x; i < NTOK; i += 256) s += row_loss[i];
  sh[threadIdx.x] = s;
  __syncthreads();
  for (int k = 128; k; k >>= 1) {
    if (threadIdx.x < k) sh[threadIdx.x] += sh[threadIdx.x + k];
    __syncthreads();
  }
  if (threadIdx.x == 0) *out_loss = sh[0] * (1.f / NTOK);
}

extern "C" void kernel_launch(void* const* d_in, const int* in_sizes, int n_in,
                              void* d_out, int out_size, void* d_ws, size_t ws_size,
                              hipStream_t stream) {
  const int*   idx     = (const int*)d_in[0];
  const int*   targets = (const int*)d_in[1];
  const float* tok     = (const float*)d_in[2];
  const float* pos     = (const float*)d_in[3];
  const float* Wq      = (const float*)d_in[4];
  const float* Wk      = (const float*)d_in[5];
  const float* Wv      = (const float*)d_in[6];
  const float* Wo      = (const float*)d_in[7];
  const float* bo      = (const float*)d_in[8];
  const float* ln1g    = (const float*)d_in[9];
  const float* ln1b    = (const float*)d_in[10];
  const float* W1      = (const float*)d_in[11];
  const float* b1      = (const float*)d_in[12];
  const float* W2      = (const float*)d_in[13];
  const float* b2      = (const float*)d_in[14];
  const float* ln2g    = (const float*)d_in[15];
  const float* ln2b    = (const float*)d_in[16];
  const float* lnfg    = (const float*)d_in[17];
  const float* lnfb    = (const float*)d_in[18];
  const float* Wlm     = (const float*)d_in[19];
  const float* blm     = (const float*)d_in[20];
  float* out = (float*)d_out;

  char* w = (char*)d_ws;
  __hip_bfloat16* x     = (__hip_bfloat16*)w; w += (size_t)NTOK * NE * 2;
  __hip_bfloat16* hbf   = (__hip_bfloat16*)w; w += (size_t)NTOK * KP * 2;
  __hip_bfloat16* hattn = (__hip_bfloat16*)w; w += (size_t)NTOK * KP * 2;
  __hip_bfloat16* WqkvH = (__hip_bfloat16*)w; w += (size_t)P_QKVH * 2;
  __hip_bfloat16* WoT   = (__hip_bfloat16*)w; w += (size_t)P_O * 2;
  __hip_bfloat16* W1T   = (__hip_bfloat16*)w; w += (size_t)P_1 * 2;
  __hip_bfloat16* W2T   = (__hip_bfloat16*)w; w += (size_t)P_2 * 2;
  __hip_bfloat16* WlmT  = (__hip_bfloat16*)w; w += (size_t)P_LM * 2;
  float* row_loss = (float*)w;              w += (size_t)NTOK * 4;
  float* esum     = (float*)w;              // NTOK*24*4 = 6.3 MB

  k_prep_all<<<(P_QKVH + P_O + P_1 + P_2 + P_LM) / 256, 256, 0, stream>>>(
      Wq, Wk, Wv, Wo, W1, W2, Wlm, WqkvH, WoT, W1T, W2T, WlmT);
  k_embed_ln<<<NTOK / 4, 256, 0, stream>>>(idx, tok, pos, ln1g, ln1b, x, hbf, hattn);

  for (int l = 0; l < NL; l++) {
    k_qkv_attn<<<BBATCH * NHD, 512, 0, stream>>>(
        hbf, WqkvH + (size_t)l * NHD * 256 * KP, hattn);
    const float* gnp = (l < NL - 1) ? (ln1g + (l + 1) * NE) : lnfg;
    const float* bnp = (l < NL - 1) ? (ln1b + (l + 1) * NE) : lnfb;
    k_wo_mlp_ln<<<512, 512, 0, stream>>>(
        hattn, WoT + (size_t)l * 256 * KP, bo + l * NE,
        W1T + (size_t)l * 896 * KP, b1 + l * 832,
        W2T + (size_t)l * 256 * 832, b2 + l * NE,
        ln2g + l * NE, ln2b + l * NE, gnp, bnp, x, hbf);
  }

  k_mgemm<false, true, false, true><<<dim3(12, 512), 256, 0, stream>>>(
      hbf, KP, WlmT, KP, blm, out, VOCAB, VOCAB, KP, esum);

  k_loss_fin<<<NTOK / 256, 256, 0, stream>>>(esum, out, targets, row_loss);
  k_loss_reduce<<<1, 256, 0, stream>>>(row_loss, out + ((size_t)out_size - 1));
}

// Round 18
// 2115.171 us; speedup vs baseline: 1.0256x; 1.0256x over previous
//
#include <hip/hip_runtime.h>
#include <hip/hip_bf16.h>
#include <math.h>

#define VOCAB 1500
#define NE    208
#define TT    256
#define NHD   4
#define HD    52
#define NL    8
#define BBATCH 256
#define NTOK  (BBATCH * TT)   // 65536
#define KP    224             // NE padded to multiple of 32

typedef __attribute__((ext_vector_type(8))) short bf16x8;
typedef __attribute__((ext_vector_type(4))) short s16x4;
typedef __attribute__((ext_vector_type(4))) float f32x4;
typedef __attribute__((ext_vector_type(4))) int i32x4;
typedef __attribute__((ext_vector_type(4))) _Float16 f16x4;

__device__ __forceinline__ void gload16(const void* g, void* l) {
  __builtin_amdgcn_global_load_lds(
      (const __attribute__((address_space(1))) unsigned int*)g,
      (__attribute__((address_space(3))) unsigned int*)l, 16, 0, 0);
}
__device__ __forceinline__ float bf2f(short u) {
  union { unsigned int i; float f; } cv;
  cv.i = ((unsigned int)(unsigned short)u) << 16;
  return cv.f;
}
__device__ __forceinline__ short f2bf(float f) {
  return (short)__bfloat16_as_ushort(__float2bfloat16(f));
}

// ---------- merged weight prep: all transposed/padded bf16 copies ----------
// QKV packed per-head: [NL][NHD][256][KP], rows: q 0-51 | k 52-103 | v 104-155 | 0
#define P_QKVH 1835008           // NL*NHD*256*KP
#define P_O    458752            // NL*256*KP
#define P_1    1605632           // NL*896*KP
#define P_2    1703936           // NL*256*832
#define P_LM   344064            // 1536*KP
__global__ __launch_bounds__(256) void k_prep_all(const float* __restrict__ Wq,
                                                  const float* __restrict__ Wk,
                                                  const float* __restrict__ Wv,
                                                  const float* __restrict__ Wo,
                                                  const float* __restrict__ W1,
                                                  const float* __restrict__ W2,
                                                  const float* __restrict__ Wlm,
                                                  __hip_bfloat16* __restrict__ qkvH,
                                                  __hip_bfloat16* __restrict__ oT,
                                                  __hip_bfloat16* __restrict__ t1,
                                                  __hip_bfloat16* __restrict__ t2,
                                                  __hip_bfloat16* __restrict__ lmT) {
  int gi = blockIdx.x * 256 + threadIdx.x;
  if (gi < P_QKVH) {
    int i = gi;
    int c = i % KP;
    int rhl = i / KP;
    int r = rhl % 256, hl = rhl / 256;
    int h = hl % NHD, l = hl / NHD;
    float v = 0.f;
    if (c < NE && r < 156) {
      const float* W = (r < 52) ? Wq : (r < 104) ? Wk : Wv;
      int d = (r < 52) ? r : (r < 104) ? r - 52 : r - 104;
      v = W[(((size_t)l * NHD + h) * NE + c) * HD + d];
    }
    qkvH[i] = __float2bfloat16(v);
  } else if (gi < P_QKVH + P_O) {
    int i = gi - P_QKVH;
    int c = i % KP;
    int jl = i / KP;
    int j = jl % 256, l = jl / 256;
    float v = (j < NE && c < NE) ? Wo[((size_t)l * NE + c) * NE + j] : 0.f;
    oT[i] = __float2bfloat16(v);
  } else if (gi < P_QKVH + P_O + P_1) {
    int i = gi - (P_QKVH + P_O);
    int c = i % KP;
    int jl = i / KP;
    int j = jl % 896, l = jl / 896;
    float v = (j < 832 && c < NE) ? W1[((size_t)l * NE + c) * 832 + j] : 0.f;
    t1[i] = __float2bfloat16(v);
  } else if (gi < P_QKVH + P_O + P_1 + P_2) {
    int i = gi - (P_QKVH + P_O + P_1);
    int c = i % 832;
    int jl = i / 832;
    int j = jl % 256, l = jl / 256;
    float v = (j < NE) ? W2[((size_t)l * 832 + c) * NE + j] : 0.f;
    t2[i] = __float2bfloat16(v);
  } else {
    int i = gi - (P_QKVH + P_O + P_1 + P_2);
    int c = i % KP;
    int j = i / KP;
    float v = (j < VOCAB && c < NE) ? Wlm[(size_t)c * VOCAB + j] : 0.f;
    lmT[i] = __float2bfloat16(v);
  }
}

// --- fused embedding + LayerNorm1; also zero hattn pad cols (once) ---------
__global__ __launch_bounds__(256) void k_embed_ln(const int* __restrict__ idx,
                                                  const float* __restrict__ tok,
                                                  const float* __restrict__ pos,
                                                  const float* __restrict__ g,
                                                  const float* __restrict__ b,
                                                  __hip_bfloat16* __restrict__ x,
                                                  __hip_bfloat16* __restrict__ h,
                                                  __hip_bfloat16* __restrict__ hattn) {
  int r = blockIdx.x * 4 + (threadIdx.x >> 6);
  int lane = threadIdx.x & 63;
  const int c0 = lane * 4;
  const int t = r & (TT - 1);
  float v[4] = {0.f, 0.f, 0.f, 0.f};
  float s = 0.f;
  if (lane < 52) {
    float4 tv = *(const float4*)(tok + (size_t)idx[r] * NE + c0);
    float4 pv = *(const float4*)(pos + (size_t)t * NE + c0);
    v[0] = tv.x + pv.x; v[1] = tv.y + pv.y;
    v[2] = tv.z + pv.z; v[3] = tv.w + pv.w;
    s = v[0] + v[1] + v[2] + v[3];
  }
  #pragma unroll
  for (int o = 32; o; o >>= 1) s += __shfl_xor(s, o);
  float mu = s * (1.f / NE);
  float q = 0.f;
  if (lane < 52) {
    #pragma unroll
    for (int i = 0; i < 4; i++) { float d = v[i] - mu; q += d * d; }
  }
  #pragma unroll
  for (int o = 32; o; o >>= 1) q += __shfl_xor(q, o);
  float inv = rsqrtf(q * (1.f / NE) + 1e-5f);
  if (lane < 52) {
    s16x4 xv;
    #pragma unroll
    for (int i = 0; i < 4; i++) xv[i] = f2bf(v[i]);
    *(s16x4*)(x + (size_t)r * NE + c0) = xv;
  }
  if (lane < 56) {
    s16x4 outv = {};
    if (lane < 52) {
      #pragma unroll
      for (int i = 0; i < 4; i++)
        outv[i] = f2bf((v[i] - mu) * inv * g[c0 + i] + b[c0 + i]);
    }
    *(s16x4*)(h + (size_t)r * KP + c0) = outv;
    if (lane >= 52)   // zero hattn pad cols 208..223 (never written by attn)
      *(s16x4*)(hattn + (size_t)r * KP + c0) = (s16x4){};
  }
}

// ------- bf16 MFMA GEMM (LM head) + XCD swizzle + fused exp-sum ------------
template <bool RELU, bool BIAS, bool OUTBF, bool EXPSUM>
__global__ __launch_bounds__(256) void k_mgemm(const __hip_bfloat16* __restrict__ A, int lda,
                                               const __hip_bfloat16* __restrict__ BT, int ldb,
                                               const float* __restrict__ bias,
                                               void* __restrict__ Cout, int ldc,
                                               int N, int K,
                                               float* __restrict__ esum) {
  __shared__ __hip_bfloat16 As[2][128 * 32];
  __shared__ __hip_bfloat16 Bs[2][128 * 32];
  const int gx = gridDim.x;
  const int id = blockIdx.x + gx * blockIdx.y;
  const int qq = (gx * gridDim.y) >> 3;          // nwg % 8 == 0 (gridDim.y=512)
  const int wid2 = (id & 7) * qq + (id >> 3);
  const int by = wid2 / gx, bx = wid2 - by * gx;
  const int bm = by * 128, bn = bx * 128;
  const int tid = threadIdx.x;
  const int wave = tid >> 6, lane = tid & 63;
  const int wr = (wave >> 1) * 64, wc = (wave & 1) * 64;
  const int l15 = lane & 15, l4 = lane >> 4;
  const int srow = tid >> 2, sgrp = (tid & 3) * 8;
  const int srow2 = srow + 64;
  f32x4 acc[4][4] = {};
  const int nt = K / 32;
  gload16(A + (size_t)(bm + srow) * lda + sgrp, &As[0][tid * 8]);
  gload16(BT + (size_t)(bn + srow) * ldb + sgrp, &Bs[0][tid * 8]);
  gload16(A + (size_t)(bm + srow2) * lda + sgrp, &As[0][(256 + tid) * 8]);
  gload16(BT + (size_t)(bn + srow2) * ldb + sgrp, &Bs[0][(256 + tid) * 8]);
  int cur = 0;
  for (int t = 0; t < nt; t++) {
    if (t + 1 < nt) {
      int k1 = (t + 1) * 32;
      gload16(A + (size_t)(bm + srow) * lda + k1 + sgrp, &As[cur ^ 1][tid * 8]);
      gload16(BT + (size_t)(bn + srow) * ldb + k1 + sgrp, &Bs[cur ^ 1][tid * 8]);
      gload16(A + (size_t)(bm + srow2) * lda + k1 + sgrp, &As[cur ^ 1][(256 + tid) * 8]);
      gload16(BT + (size_t)(bn + srow2) * ldb + k1 + sgrp, &Bs[cur ^ 1][(256 + tid) * 8]);
      asm volatile("s_waitcnt vmcnt(4)" ::: "memory");
    } else {
      asm volatile("s_waitcnt vmcnt(0)" ::: "memory");
    }
    __builtin_amdgcn_s_barrier();
    bf16x8 af[4], bfr[4];
    #pragma unroll
    for (int m = 0; m < 4; m++)
      af[m] = *(const bf16x8*)&As[cur][(wr + m * 16 + l15) * 32 + l4 * 8];
    #pragma unroll
    for (int n = 0; n < 4; n++)
      bfr[n] = *(const bf16x8*)&Bs[cur][(wc + n * 16 + l15) * 32 + l4 * 8];
    #pragma unroll
    for (int m = 0; m < 4; m++)
      #pragma unroll
      for (int n = 0; n < 4; n++)
        acc[m][n] = __builtin_amdgcn_mfma_f32_16x16x32_bf16(af[m], bfr[n], acc[m][n], 0, 0, 0);
    if (t + 1 < nt) __builtin_amdgcn_s_barrier();
    cur ^= 1;
  }
  float es[4][4];
  if (EXPSUM) {
    #pragma unroll
    for (int m = 0; m < 4; m++)
      #pragma unroll
      for (int j = 0; j < 4; j++) es[m][j] = 0.f;
  }
  #pragma unroll
  for (int m = 0; m < 4; m++) {
    #pragma unroll
    for (int n = 0; n < 4; n++) {
      int col = bn + wc + n * 16 + l15;
      if (col < N) {
        float bv = BIAS ? bias[col] : 0.f;
        #pragma unroll
        for (int j = 0; j < 4; j++) {
          int row = bm + wr + m * 16 + l4 * 4 + j;
          float v = acc[m][n][j] + bv;
          if (RELU) v = fmaxf(v, 0.f);
          size_t off = (size_t)row * ldc + col;
          if (OUTBF) ((__hip_bfloat16*)Cout)[off] = __float2bfloat16(v);
          else       ((float*)Cout)[off] = v;
          if (EXPSUM) es[m][j] += __expf(v);   // |v| small: no-max exp safe
        }
      }
    }
  }
  if (EXPSUM) {
    #pragma unroll
    for (int m = 0; m < 4; m++)
      #pragma unroll
      for (int j = 0; j < 4; j++) {
        float e = es[m][j];
        #pragma unroll
        for (int off = 1; off < 16; off <<= 1) e += __shfl_xor(e, off);
        if (l15 == 0) {
          int row = bm + wr + m * 16 + l4 * 4 + j;
          esum[(size_t)row * 24 + bx * 2 + (wave & 1)] = e;
        }
      }
  }
}

// ---- fused per-head QKV GEMM + flash attention: one block per (b,h) -------
__global__ __launch_bounds__(512) void k_qkv_attn(const __hip_bfloat16* __restrict__ hbf,
                                                  const __hip_bfloat16* __restrict__ WqkvH,
                                                  __hip_bfloat16* __restrict__ o) {
  __shared__ __hip_bfloat16 As2[2][256 * 32];   // 32 KB
  __shared__ __hip_bfloat16 Bs2[2][256 * 32];   // 32 KB
  __shared__ __hip_bfloat16 Ks[256 * 64];       // 32 KB
  __shared__ _Float16      Vt[64 * 260];        // 32.5 KB
  __shared__ __hip_bfloat16 Qs[256 * 56];       // 28 KB   (total 156.5 KB)
  const int bh0 = blockIdx.x;
  const int bh = (bh0 & 7) * 128 + (bh0 >> 3);  // 4 heads of b on one XCD
  const int b = bh >> 2, h = bh & 3;
  const __hip_bfloat16* A = hbf + (size_t)b * TT * KP;
  const __hip_bfloat16* B = WqkvH + (size_t)h * 256 * KP;
  const int tid = threadIdx.x;
  const int w = tid >> 6, lane = tid & 63, l15 = lane & 15, l4 = lane >> 4;
  // ---------------- phase 1: QKV GEMM ----------------
  {
    const int s0 = tid, s1 = tid + 512;
    const int r0 = s0 >> 2, g0 = (s0 & 3) * 8;
    const int r1 = s1 >> 2, g1 = (s1 & 3) * 8;
    f32x4 acc[2][10] = {};
    gload16(A + (size_t)r0 * KP + g0, &As2[0][s0 * 8]);
    gload16(A + (size_t)r1 * KP + g1, &As2[0][s1 * 8]);
    gload16(B + (size_t)r0 * KP + g0, &Bs2[0][s0 * 8]);
    gload16(B + (size_t)r1 * KP + g1, &Bs2[0][s1 * 8]);
    int cur = 0;
    for (int t = 0; t < 7; t++) {
      if (t < 6) {
        int k1 = (t + 1) * 32;
        gload16(A + (size_t)r0 * KP + k1 + g0, &As2[cur ^ 1][s0 * 8]);
        gload16(A + (size_t)r1 * KP + k1 + g1, &As2[cur ^ 1][s1 * 8]);
        gload16(B + (size_t)r0 * KP + k1 + g0, &Bs2[cur ^ 1][s0 * 8]);
        gload16(B + (size_t)r1 * KP + k1 + g1, &Bs2[cur ^ 1][s1 * 8]);
        asm volatile("s_waitcnt vmcnt(4)" ::: "memory");
      } else {
        asm volatile("s_waitcnt vmcnt(0)" ::: "memory");
      }
      __builtin_amdgcn_s_barrier();
      bf16x8 af[2], bfr[10];
      #pragma unroll
      for (int m = 0; m < 2; m++)
        af[m] = *(const bf16x8*)&As2[cur][(w * 32 + m * 16 + l15) * 32 + l4 * 8];
      #pragma unroll
      for (int n = 0; n < 10; n++)
        bfr[n] = *(const bf16x8*)&Bs2[cur][(n * 16 + l15) * 32 + l4 * 8];
      #pragma unroll
      for (int m = 0; m < 2; m++)
        #pragma unroll
        for (int n = 0; n < 10; n++)
          acc[m][n] = __builtin_amdgcn_mfma_f32_16x16x32_bf16(af[m], bfr[n], acc[m][n], 0, 0, 0);
      if (t < 6) __builtin_amdgcn_s_barrier();
      cur ^= 1;
    }
    // scatter: Q -> Qs[t][d], K -> Ks[t][d], V -> Vt[d][t] (f32->f16 direct)
    #pragma unroll
    for (int m = 0; m < 2; m++)
      #pragma unroll
      for (int n = 0; n < 10; n++) {
        int col = n * 16 + l15;
        #pragma unroll
        for (int j = 0; j < 4; j++) {
          int trow = w * 32 + m * 16 + l4 * 4 + j;
          float v = acc[m][n][j];
          if (col < 52)        Qs[trow * 56 + col] = __float2bfloat16(v);
          else if (col < 104)  Ks[trow * 64 + (col - 52)] = __float2bfloat16(v);
          else if (col < 156)  Vt[(col - 104) * 260 + trow] = (_Float16)v;
        }
      }
  }
  // zero pads (R9 lesson: uninit LDS can be NaN bits; every read slot written)
  for (int i = tid; i < 768; i += 512) {        // Ks cols 52..63
    int row = i / 3, cc = 52 + (i % 3) * 4;
    *(s16x4*)&Ks[row * 64 + cc] = (s16x4){};
  }
  for (int i = tid; i < 3072; i += 512)         // Vt rows 52..63
    Vt[(52 + i / 256) * 260 + (i & 255)] = (_Float16)0.f;
  if (tid < 256)                                // Qs cols 52..55
    *(s16x4*)&Qs[tid * 56 + 52] = (s16x4){};
  __syncthreads();
  // ---------------- phase 2: attention ----------------
  const float scale = 0.06933752453f;  // NE**-0.5 (reference scales by n_embed)
  const int qts[2] = {w, 15 - w};
  bf16x8 qf[2][2];
  #pragma unroll
  for (int i = 0; i < 2; i++)
    #pragma unroll
    for (int ks = 0; ks < 2; ks++) {
      int s = ks * 32 + l4 * 8;
      qf[i][ks] = (s <= 48) ? *(const bf16x8*)&Qs[(qts[i] * 16 + l15) * 56 + s]
                            : (bf16x8){};
    }
  f32x4 oacc[4][2] = {};
  float mrun[2] = {-1e30f, -1e30f};
  float lrun[2] = {0.f, 0.f};
  const int cmax = 15 - w;
  for (int c = 0; c <= cmax; c++) {
    const int kb = c * 16;
    const bf16x8 kf0 = *(const bf16x8*)&Ks[(kb + l15) * 64 + l4 * 8];
    const bf16x8 kf1 = *(const bf16x8*)&Ks[(kb + l15) * 64 + 32 + l4 * 8];
    #pragma unroll
    for (int i = 0; i < 2; i++) {
      if (qts[i] < c) continue;
      __builtin_amdgcn_s_setprio(1);
      f32x4 s4 = __builtin_amdgcn_mfma_f32_16x16x32_bf16(kf0, qf[i][0],
                                                         (f32x4){0.f, 0.f, 0.f, 0.f}, 0, 0, 0);
      s4 = __builtin_amdgcn_mfma_f32_16x16x32_bf16(kf1, qf[i][1], s4, 0, 0, 0);
      __builtin_amdgcn_s_setprio(0);
      const int q = qts[i] * 16 + l15;
      float pv[4];
      float pmax = -1e30f;
      #pragma unroll
      for (int j = 0; j < 4; j++) {
        int key = kb + l4 * 4 + j;
        float s = s4[j] * scale;
        pv[j] = (key <= q) ? s : -1e30f;
        pmax = fmaxf(pmax, pv[j]);
      }
      pmax = fmaxf(pmax, __shfl_xor(pmax, 16));
      pmax = fmaxf(pmax, __shfl_xor(pmax, 32));
      if (!__all(pmax - mrun[i] <= 8.f)) {     // T13 defer-rescale
        const float newm = fmaxf(mrun[i], pmax);
        const float r = __expf(mrun[i] - newm);
        lrun[i] *= r;
        mrun[i] = newm;
        #pragma unroll
        for (int m = 0; m < 4; m++) {
          oacc[m][i][0] *= r; oacc[m][i][1] *= r;
          oacc[m][i][2] *= r; oacc[m][i][3] *= r;
        }
      }
      float psum = 0.f;
      f16x4 pb;
      #pragma unroll
      for (int j = 0; j < 4; j++) {
        float e = __expf(pv[j] - mrun[i]);   // bounded by e^8
        psum += e;
        pb[j] = (_Float16)e;
      }
      psum += __shfl_xor(psum, 16);
      psum += __shfl_xor(psum, 32);
      lrun[i] += psum;
      __builtin_amdgcn_s_setprio(1);
      #pragma unroll
      for (int m = 0; m < 4; m++) {
        f16x4 vf = *(const f16x4*)&Vt[(m * 16 + l15) * 260 + kb + l4 * 4];
        oacc[m][i] = __builtin_amdgcn_mfma_f32_16x16x16f16(vf, pb, oacc[m][i], 0, 0, 0);
      }
      __builtin_amdgcn_s_setprio(0);
    }
  }
  #pragma unroll
  for (int i = 0; i < 2; i++) {
    const float inv = 1.f / lrun[i];
    __hip_bfloat16* orow = o + (size_t)(b * TT + qts[i] * 16 + l15) * KP + h * HD;
    #pragma unroll
    for (int m = 0; m < 4; m++) {
      int d0 = m * 16 + l4 * 4;
      if (d0 + 3 < HD) {               // 13 packed 8B stores
        s16x4 pk;
        #pragma unroll
        for (int j = 0; j < 4; j++) pk[j] = f2bf(oacc[m][i][j] * inv);
        *(s16x4*)(orow + d0) = pk;
      }
    }
  }
}

// ---- fused layer-2nd-half: x''=x+attn@Wo+bo thru MLP, dual LN, 1 kernel ---
__global__ __launch_bounds__(512) void k_wo_mlp_ln(const __hip_bfloat16* __restrict__ hattn,
                                                   const __hip_bfloat16* __restrict__ WoT,
                                                   const float* __restrict__ bo,
                                                   const __hip_bfloat16* __restrict__ W1T,
                                                   const float* __restrict__ b1,
                                                   const __hip_bfloat16* __restrict__ W2T,
                                                   const float* __restrict__ b2,
                                                   const float* __restrict__ g2,
                                                   const float* __restrict__ bb2,
                                                   const float* __restrict__ gn,
                                                   const float* __restrict__ bn,
                                                   __hip_bfloat16* __restrict__ xio,
                                                   __hip_bfloat16* __restrict__ hout) {
  __shared__ __hip_bfloat16 Hs[128 * 232];       // 59.4 KB (LN(x'), MLP A-tile)
  __shared__ __hip_bfloat16 pool[39936];         // 78 KB union
  __hip_bfloat16 (*As)[128 * 32] = (__hip_bfloat16 (*)[128 * 32])pool;
  __hip_bfloat16 (*Bs)[256 * 32] = (__hip_bfloat16 (*)[256 * 32])(pool + 8192);
  __hip_bfloat16* W1s = pool;
  __hip_bfloat16* Ac  = pool + 14336;
  __hip_bfloat16 (*W2s)[256 * 32] = (__hip_bfloat16 (*)[256 * 32])(pool + 23552);
  __shared__ float sred[128][4], qred[128][4];
  const int bm = blockIdx.x * 128;
  const int tid = threadIdx.x;
  const int wid = tid >> 6, lane = tid & 63;
  const int l15 = lane & 15, l4 = lane >> 4;
  const int w2r = (wid >> 2) * 64, w2c = (wid & 3) * 64;
  const int w1r = (wid >> 1) * 32, w1c = (wid & 1) * 32;
  const int srow = tid >> 2, sgrp = (tid & 3) * 8;
  // ---------------- Phase A: Wo GEMM (K=224), acc = xp ----------------
  f32x4 xp[4][4] = {};
  {
    gload16(hattn + (size_t)(bm + srow) * KP + sgrp, &As[0][tid * 8]);
    gload16(WoT + (size_t)srow * KP + sgrp, &Bs[0][tid * 8]);
    gload16(WoT + (size_t)(128 + srow) * KP + sgrp, &Bs[0][(512 + tid) * 8]);
    int cur = 0;
    for (int t = 0; t < 7; t++) {
      if (t + 1 < 7) {
        int k1 = (t + 1) * 32;
        gload16(hattn + (size_t)(bm + srow) * KP + k1 + sgrp, &As[cur ^ 1][tid * 8]);
        gload16(WoT + (size_t)srow * KP + k1 + sgrp, &Bs[cur ^ 1][tid * 8]);
        gload16(WoT + (size_t)(128 + srow) * KP + k1 + sgrp, &Bs[cur ^ 1][(512 + tid) * 8]);
        asm volatile("s_waitcnt vmcnt(3)" ::: "memory");
      } else {
        asm volatile("s_waitcnt vmcnt(0)" ::: "memory");
      }
      __builtin_amdgcn_s_barrier();
      bf16x8 af[4], bfr[4];
      #pragma unroll
      for (int m = 0; m < 4; m++)
        af[m] = *(const bf16x8*)&As[cur][(w2r + m * 16 + l15) * 32 + l4 * 8];
      #pragma unroll
      for (int n = 0; n < 4; n++)
        bfr[n] = *(const bf16x8*)&Bs[cur][(w2c + n * 16 + l15) * 32 + l4 * 8];
      #pragma unroll
      for (int m = 0; m < 4; m++)
        #pragma unroll
        for (int n = 0; n < 4; n++)
          xp[m][n] = __builtin_amdgcn_mfma_f32_16x16x32_bf16(af[m], bfr[n], xp[m][n], 0, 0, 0);
      if (t + 1 < 7) __builtin_amdgcn_s_barrier();
      cur ^= 1;
    }
  }
  // ---- Epi A: x' = acc + bo + x (regs); LN2 stats; LN(x') -> Hs ----
  #pragma unroll
  for (int m = 0; m < 4; m++)
    #pragma unroll
    for (int j = 0; j < 4; j++) {
      int rowL = w2r + m * 16 + l4 * 4 + j;
      float s = 0.f, q = 0.f;
      #pragma unroll
      for (int n = 0; n < 4; n++) {
        int col = w2c + n * 16 + l15;
        float v = 0.f;
        if (col < NE)
          v = xp[m][n][j] + bo[col] +
              bf2f(((const short*)xio)[(size_t)(bm + rowL) * NE + col]);
        xp[m][n][j] = v;
        s += v; q += v * v;
      }
      #pragma unroll
      for (int off = 1; off < 16; off <<= 1) {
        s += __shfl_xor(s, off);
        q += __shfl_xor(q, off);
      }
      if (l15 == 0) { sred[rowL][wid & 3] = s; qred[rowL][wid & 3] = q; }
    }
  __syncthreads();   // sred/qred ready; all As/Bs ds_reads done
  #pragma unroll
  for (int m = 0; m < 4; m++)
    #pragma unroll
    for (int j = 0; j < 4; j++) {
      int rowL = w2r + m * 16 + l4 * 4 + j;
      float s = sred[rowL][0] + sred[rowL][1] + sred[rowL][2] + sred[rowL][3];
      float q = qred[rowL][0] + qred[rowL][1] + qred[rowL][2] + qred[rowL][3];
      float mu = s * (1.f / NE);
      float var = q * (1.f / NE) - mu * mu;
      float inv = rsqrtf(var + 1e-5f);
      #pragma unroll
      for (int n = 0; n < 4; n++) {
        int col = w2c + n * 16 + l15;
        if (col < NE)
          Hs[rowL * 232 + col] =
              __float2bfloat16((xp[m][n][j] - mu) * inv * g2[col] + bb2[col]);
      }
    }
  {
    int row = tid >> 2, c0 = 208 + (tid & 3) * 4;
    *(s16x4*)&Hs[row * 232 + c0] = (s16x4){};
  }
  __syncthreads();
  // ---------------- Phase C: MLP 13 chunks ----------------
  f32x4 acc2[4][4] = {};
  for (int jc = 0; jc < 13; jc++) {
    if (jc) __syncthreads();
    for (int s = tid; s < 1792; s += 512)
      gload16(W1T + (size_t)(jc * 64 + s / 28) * KP + (s % 28) * 8, &W1s[s * 8]);
    for (int s = tid; s < 2048; s += 512) {
      int kt2 = s >> 10, ss = s & 1023;
      gload16(W2T + (size_t)(ss >> 2) * 832 + jc * 64 + kt2 * 32 + (ss & 3) * 8,
              &W2s[kt2][ss * 8]);
    }
    __syncthreads();
    f32x4 acc1[2][2] = {};
    #pragma unroll
    for (int kt = 0; kt < 7; kt++) {
      bf16x8 a0 = *(const bf16x8*)&Hs[(w1r + l15) * 232 + kt * 32 + l4 * 8];
      bf16x8 a1 = *(const bf16x8*)&Hs[(w1r + 16 + l15) * 232 + kt * 32 + l4 * 8];
      bf16x8 c0 = *(const bf16x8*)&W1s[(w1c + l15) * 224 + kt * 32 + l4 * 8];
      bf16x8 c1 = *(const bf16x8*)&W1s[(w1c + 16 + l15) * 224 + kt * 32 + l4 * 8];
      acc1[0][0] = __builtin_amdgcn_mfma_f32_16x16x32_bf16(a0, c0, acc1[0][0], 0, 0, 0);
      acc1[0][1] = __builtin_amdgcn_mfma_f32_16x16x32_bf16(a0, c1, acc1[0][1], 0, 0, 0);
      acc1[1][0] = __builtin_amdgcn_mfma_f32_16x16x32_bf16(a1, c0, acc1[1][0], 0, 0, 0);
      acc1[1][1] = __builtin_amdgcn_mfma_f32_16x16x32_bf16(a1, c1, acc1[1][1], 0, 0, 0);
    }
    #pragma unroll
    for (int m = 0; m < 2; m++)
      #pragma unroll
      for (int n = 0; n < 2; n++) {
        int colL = w1c + n * 16 + l15;
        float bv = b1[jc * 64 + colL];
        #pragma unroll
        for (int j = 0; j < 4; j++) {
          int rowL = w1r + m * 16 + l4 * 4 + j;
          Ac[rowL * 72 + colL] = __float2bfloat16(fmaxf(acc1[m][n][j] + bv, 0.f));
        }
      }
    __syncthreads();
    #pragma unroll
    for (int kt2 = 0; kt2 < 2; kt2++) {
      bf16x8 af[4], bfr[4];
      #pragma unroll
      for (int m = 0; m < 4; m++)
        af[m] = *(const bf16x8*)&Ac[(w2r + m * 16 + l15) * 72 + kt2 * 32 + l4 * 8];
      #pragma unroll
      for (int n = 0; n < 4; n++)
        bfr[n] = *(const bf16x8*)&W2s[kt2][(w2c + n * 16 + l15) * 32 + l4 * 8];
      #pragma unroll
      for (int m = 0; m < 4; m++)
        #pragma unroll
        for (int n = 0; n < 4; n++)
          acc2[m][n] = __builtin_amdgcn_mfma_f32_16x16x32_bf16(af[m], bfr[n], acc2[m][n], 0, 0, 0);
    }
  }
  // ---- Epi C: x'' = xp + mlp + b2; LN-next; stores ----
  #pragma unroll
  for (int m2 = 0; m2 < 4; m2++)
    #pragma unroll
    for (int j = 0; j < 4; j++) {
      int rowL = w2r + m2 * 16 + l4 * 4 + j;
      float s = 0.f, q = 0.f;
      #pragma unroll
      for (int n2 = 0; n2 < 4; n2++) {
        int col = w2c + n2 * 16 + l15;
        float v = 0.f;
        if (col < NE) v = acc2[m2][n2][j] + b2[col] + xp[m2][n2][j];
        acc2[m2][n2][j] = v;
        s += v; q += v * v;
      }
      #pragma unroll
      for (int off = 1; off < 16; off <<= 1) {
        s += __shfl_xor(s, off);
        q += __shfl_xor(q, off);
      }
      if (l15 == 0) { sred[rowL][wid & 3] = s; qred[rowL][wid & 3] = q; }
    }
  __syncthreads();
  #pragma unroll
  for (int m2 = 0; m2 < 4; m2++)
    #pragma unroll
    for (int j = 0; j < 4; j++) {
      int rowL = w2r + m2 * 16 + l4 * 4 + j;
      float s = sred[rowL][0] + sred[rowL][1] + sred[rowL][2] + sred[rowL][3];
      float q = qred[rowL][0] + qred[rowL][1] + qred[rowL][2] + qred[rowL][3];
      float mu = s * (1.f / NE);
      float var = q * (1.f / NE) - mu * mu;
      float inv = rsqrtf(var + 1e-5f);
      size_t row = bm + rowL;
      #pragma unroll
      for (int n2 = 0; n2 < 4; n2++) {
        int col = w2c + n2 * 16 + l15;
        if (col < NE) {
          float v = acc2[m2][n2][j];
          xio[row * NE + col] = __float2bfloat16(v);
          hout[row * KP + col] = __float2bfloat16((v - mu) * inv * gn[col] + bn[col]);
        } else if (col < KP) {
          hout[row * KP + col] = __float2bfloat16(0.f);
        }
      }
    }
}

// ---------------- loss from fused exp-sums ----------------
__global__ __launch_bounds__(256) void k_loss_fin(const float* __restrict__ esum,
                                                  const float* __restrict__ logits,
                                                  const int* __restrict__ targets,
                                                  float* __restrict__ row_loss) {
  int r = blockIdx.x * 256 + threadIdx.x;
  const float* e = esum + (size_t)r * 24;
  float s = 0.f;
  #pragma unroll
  for (int i = 0; i < 24; i++) s += e[i];
  row_loss[r] = __logf(s) - logits[(size_t)r * VOCAB + targets[r]];
}

__global__ __launch_bounds__(256) void k_loss_reduce(const float* __restrict__ row_loss,
                                                     float* __restrict__ out_loss) {
  __shared__ float sh[256];
  float s = 0.f;
  for (int i = threadIdx.x; i < NTOK; i += 256) s += row_loss[i];
  sh[threadIdx.x] = s;
  __syncthreads();
  for (int k = 128; k; k >>= 1) {
    if (threadIdx.x < k) sh[threadIdx.x] += sh[threadIdx.x + k];
    __syncthreads();
  }
  if (threadIdx.x == 0) *out_loss = sh[0] * (1.f / NTOK);
}

extern "C" void kernel_launch(void* const* d_in, const int* in_sizes, int n_in,
                              void* d_out, int out_size, void* d_ws, size_t ws_size,
                              hipStream_t stream) {
  const int*   idx     = (const int*)d_in[0];
  const int*   targets = (const int*)d_in[1];
  const float* tok     = (const float*)d_in[2];
  const float* pos     = (const float*)d_in[3];
  const float* Wq      = (const float*)d_in[4];
  const float* Wk      = (const float*)d_in[5];
  const float* Wv      = (const float*)d_in[6];
  const float* Wo      = (const float*)d_in[7];
  const float* bo      = (const float*)d_in[8];
  const float* ln1g    = (const float*)d_in[9];
  const float* ln1b    = (const float*)d_in[10];
  const float* W1      = (const float*)d_in[11];
  const float* b1      = (const float*)d_in[12];
  const float* W2      = (const float*)d_in[13];
  const float* b2      = (const float*)d_in[14];
  const float* ln2g    = (const float*)d_in[15];
  const float* ln2b    = (const float*)d_in[16];
  const float* lnfg    = (const float*)d_in[17];
  const float* lnfb    = (const float*)d_in[18];
  const float* Wlm     = (const float*)d_in[19];
  const float* blm     = (const float*)d_in[20];
  float* out = (float*)d_out;

  char* w = (char*)d_ws;
  __hip_bfloat16* x     = (__hip_bfloat16*)w; w += (size_t)NTOK * NE * 2;
  __hip_bfloat16* hbf   = (__hip_bfloat16*)w; w += (size_t)NTOK * KP * 2;
  __hip_bfloat16* hattn = (__hip_bfloat16*)w; w += (size_t)NTOK * KP * 2;
  __hip_bfloat16* WqkvH = (__hip_bfloat16*)w; w += (size_t)P_QKVH * 2;
  __hip_bfloat16* WoT   = (__hip_bfloat16*)w; w += (size_t)P_O * 2;
  __hip_bfloat16* W1T   = (__hip_bfloat16*)w; w += (size_t)P_1 * 2;
  __hip_bfloat16* W2T   = (__hip_bfloat16*)w; w += (size_t)P_2 * 2;
  __hip_bfloat16* WlmT  = (__hip_bfloat16*)w; w += (size_t)P_LM * 2;
  float* row_loss = (float*)w;              w += (size_t)NTOK * 4;
  float* esum     = (float*)w;              // NTOK*24*4 = 6.3 MB

  k_prep_all<<<(P_QKVH + P_O + P_1 + P_2 + P_LM) / 256, 256, 0, stream>>>(
      Wq, Wk, Wv, Wo, W1, W2, Wlm, WqkvH, WoT, W1T, W2T, WlmT);
  k_embed_ln<<<NTOK / 4, 256, 0, stream>>>(idx, tok, pos, ln1g, ln1b, x, hbf, hattn);

  for (int l = 0; l < NL; l++) {
    k_qkv_attn<<<BBATCH * NHD, 512, 0, stream>>>(
        hbf, WqkvH + (size_t)l * NHD * 256 * KP, hattn);
    const float* gnp = (l < NL - 1) ? (ln1g + (l + 1) * NE) : lnfg;
    const float* bnp = (l < NL - 1) ? (ln1b + (l + 1) * NE) : lnfb;
    k_wo_mlp_ln<<<512, 512, 0, stream>>>(
        hattn, WoT + (size_t)l * 256 * KP, bo + l * NE,
        W1T + (size_t)l * 896 * KP, b1 + l * 832,
        W2T + (size_t)l * 256 * 832, b2 + l * NE,
        ln2g + l * NE, ln2b + l * NE, gnp, bnp, x, hbf);
  }

  k_mgemm<false, true, false, true><<<dim3(12, 512), 256, 0, stream>>>(
      hbf, KP, WlmT, KP, blm, out, VOCAB, VOCAB, KP, esum);

  k_loss_fin<<<NTOK / 256, 256, 0, stream>>>(esum, out, targets, row_loss);
  k_loss_reduce<<<1, 256, 0, stream>>>(row_loss, out + ((size_t)out_size - 1));
}